// Round 2
// baseline (256.585 us; speedup 1.0000x reference)
//
#include <hip/hip_runtime.h>

typedef short short8 __attribute__((ext_vector_type(8)));
typedef float f32x4 __attribute__((ext_vector_type(4)));
typedef unsigned int uint4v __attribute__((ext_vector_type(4)));

#define H_ 384
#define W_ 384
#define C_ 32
#define F_ 32
#define HW_ 147456          // H_*W_
#define HP1F 385.0f         // (H+2*pad)-1 as float
#define NB 2                // pixel batches per wave

__device__ __forceinline__ unsigned short f2bf(float f) {
  unsigned int u = __float_as_uint(f);
  u += 0x7fffu + ((u >> 16) & 1u);   // RNE
  return (unsigned short)(u >> 16);
}

__global__ __launch_bounds__(256, 4) void deform_conv_kernel(
    const float* __restrict__ x, const float* __restrict__ off,
    const float* __restrict__ kern, const float* __restrict__ bias,
    float* __restrict__ out) {
  // LDS: 9216 shorts (18.4 KB) holding the packed bf16 B fragments (MFMA
  // B-operand layout) for all 9 taps x 2 f-tiles. Written once, one barrier,
  // then read-only for the whole kernel (2 conflict-free ds_read_b128 per
  // tap). No A-side LDS at all: each lane computes its own A fragment
  // directly (pixel = lane&15 = A row, channels qq*8..+7 = its K slice),
  // so the R0 slab write->drain->read roundtrip is gone.
  __shared__ short ldsB[9216];

  const int tid = threadIdx.x;
  const int lane = tid & 63;

  // ---- stage packed B fragments (bf16, MFMA B-operand layout) into LDS ----
  {
    unsigned short* pk = (unsigned short*)ldsB;
    for (int e = tid; e < 1152; e += 256) {   // 2 f-tiles * 9 k-steps * 64 lanes
      const int ln = e & 63;
      const int kk = (e >> 6) % 9;
      const int nt = e / 576;
      const int f = nt * 16 + (ln & 15);
      const int q2 = ln >> 4;
      unsigned short rr[8];
#pragma unroll
      for (int i2 = 0; i2 < 8; ++i2) {
        const int c = q2 * 8 + i2;                     // contraction idx = kk*32 + c
        rr[i2] = f2bf(kern[(kk * 32 + c) * 32 + f]);
      }
      uint4 w;
      w.x = rr[0] | ((unsigned)rr[1] << 16);
      w.y = rr[2] | ((unsigned)rr[3] << 16);
      w.z = rr[4] | ((unsigned)rr[5] << 16);
      w.w = rr[6] | ((unsigned)rr[7] << 16);
      *(uint4*)&pk[e * 8] = w;
    }
    __syncthreads();   // only barrier in the kernel; LDS is read-only after
  }
  const short8* bp = (const short8*)ldsB;

  const float bias0 = bias[lane & 15];
  const float bias1 = bias[16 + (lane & 15)];

  const int mrow = lane & 15;       // pixel within 16-group == MFMA A row
  const int qq = lane >> 4;         // MFMA K-quad: this lane feeds c = qq*8..+7
  const int c0 = qq * 8;

  // XCD-aware swizzle: physical block p lands on XCD p%8; give each XCD a
  // contiguous run of 288 logical blocks (96 contiguous image rows) so its
  // 4 MiB L2 holds the streaming reuse window and the halo is fetched by
  // exactly one XCD. Bijection over [0,2304): blk=8q+r -> 288r+q.
  const int lb = (blockIdx.x & 7) * 288 + (blockIdx.x >> 3);

  for (int nb = 0; nb < NB; ++nb) {
    const int g = lb * (4 * NB) + nb * 4 + (tid >> 6);   // wave-group index
    const int P0 = g << 4;                               // first of 16 pixels
    const int b = (P0 >= HW_) ? 1 : 0;
    const int rem = P0 - b * HW_;
    const int i = rem / W_;
    const int j0 = rem - i * W_;     // group never crosses a row (W%16==0)
    const int j = j0 + mrow;         // this lane's pixel column

    // Prefetch this pixel's 9 tap offsets (72B contiguous, statically
    // indexed -> registers). All loads in flight before the tap loop, so
    // branch resolution for tap kk never waits on memory.
    const float* opix = off + (size_t)(i * W_ + j) * 18;
    float2 ofs[9];
#pragma unroll
    for (int kk = 0; kk < 9; ++kk) ofs[kk] = *(const float2*)(opix + kk * 2);

    f32x4 acc0 = {bias0, bias0, bias0, bias0};
    f32x4 acc1 = {bias1, bias1, bias1, bias1};

    // ---- per-tap: gather 4 corners x 8 channels, interp, MFMA directly ----
#pragma unroll
    for (int kk = 0; kk < 9; ++kk) {
      const int di = kk / 3;
      const int dj = kk - di * 3;
      float yf = (float)(i + di) + ofs[kk].y;   // padded coords; .y = y_off
      float xf = (float)(j + dj) + ofs[kk].x;   // .x = x_off
      yf = fminf(fmaxf(yf, 0.f), HP1F);
      xf = fminf(fmaxf(xf, 0.f), HP1F);
      const float y0f = floorf(yf);
      const float x0f = floorf(xf);
      const int y0 = (int)y0f;
      const int x0 = (int)x0f;

      f32x4 vlo, vhi;
      // Fast path: all 4 corners strictly inside the image; wave-uniform
      // branch via __all (covers 16 pixels; offsets ~N(0,1)).
      const int fast = ((unsigned)(y0 - 1) < 383u) & ((unsigned)(x0 - 1) < 383u);
      if (__all(fast)) {
        const float wy1 = yf - y0f;
        const float wy0 = (y0f + 1.0f) - yf;   // == (float)y1 - yf, y1=y0+1
        const float wx1 = xf - x0f;
        const float wx0 = (x0f + 1.0f) - xf;
        const float w00 = wy0 * wx0, w01 = wy0 * wx1;
        const float w10 = wy1 * wx0, w11 = wy1 * wx1;
        const int base00 = ((b * H_ + (y0 - 1)) * W_ + (x0 - 1)) * C_ + c0;
        // 8 unconditional, independent 16B gathers -> all in flight together
        const f32x4 p00l = *(const f32x4*)(x + base00);
        const f32x4 p00h = *(const f32x4*)(x + base00 + 4);
        const f32x4 p01l = *(const f32x4*)(x + base00 + C_);
        const f32x4 p01h = *(const f32x4*)(x + base00 + C_ + 4);
        const f32x4 p10l = *(const f32x4*)(x + base00 + W_ * C_);
        const f32x4 p10h = *(const f32x4*)(x + base00 + W_ * C_ + 4);
        const f32x4 p11l = *(const f32x4*)(x + base00 + W_ * C_ + C_);
        const f32x4 p11h = *(const f32x4*)(x + base00 + W_ * C_ + C_ + 4);
        vlo = w00 * p00l + w01 * p01l + w10 * p10l + w11 * p11l;
        vhi = w00 * p00h + w01 * p01h + w10 * p10h + w11 * p11h;
      } else {
        // Slow path: verbatim R0 logic (guarded loads, pad corners -> 0).
        const int y1 = min(y0 + 1, 385);
        const int x1 = min(x0 + 1, 385);
        const float wy1 = yf - y0f;
        const float wy0 = (float)y1 - yf;
        const float wx1 = xf - x0f;
        const float wx0 = (float)x1 - xf;
        const float w00 = wy0 * wx0, w01 = wy0 * wx1;
        const float w10 = wy1 * wx0, w11 = wy1 * wx1;

        const int yu0 = y0 - 1, xu0 = x0 - 1;
        const bool vy0 = (unsigned)yu0 < 384u, vy1 = (unsigned)(y1 - 1) < 384u;
        const bool vx0 = (unsigned)xu0 < 384u, vx1 = (unsigned)(x1 - 1) < 384u;
        const int base00 = ((b * H_ + yu0) * W_ + xu0) * C_ + c0;
        const int ddx = (x1 - x0) * C_;
        const int ddy = (y1 - y0) * (W_ * C_);
        const f32x4 z = {0.f, 0.f, 0.f, 0.f};
        f32x4 p00l = z, p00h = z, p01l = z, p01h = z;
        f32x4 p10l = z, p10h = z, p11l = z, p11h = z;
        if (vy0 && vx0) { p00l = *(const f32x4*)(x + base00);
                          p00h = *(const f32x4*)(x + base00 + 4); }
        if (vy0 && vx1) { p01l = *(const f32x4*)(x + base00 + ddx);
                          p01h = *(const f32x4*)(x + base00 + ddx + 4); }
        if (vy1 && vx0) { p10l = *(const f32x4*)(x + base00 + ddy);
                          p10h = *(const f32x4*)(x + base00 + ddy + 4); }
        if (vy1 && vx1) { p11l = *(const f32x4*)(x + base00 + ddy + ddx);
                          p11h = *(const f32x4*)(x + base00 + ddy + ddx + 4); }
        vlo = w00 * p00l + w01 * p01l + w10 * p10l + w11 * p11l;
        vhi = w00 * p00h + w01 * p01h + w10 * p10h + w11 * p11h;
      }

      // pack this lane's A fragment: 8 bf16 = channels c0..c0+7 of its pixel
      const unsigned u0 = f2bf(vlo[0]) | ((unsigned)f2bf(vlo[1]) << 16);
      const unsigned u1 = f2bf(vlo[2]) | ((unsigned)f2bf(vlo[3]) << 16);
      const unsigned u2 = f2bf(vhi[0]) | ((unsigned)f2bf(vhi[1]) << 16);
      const unsigned u3 = f2bf(vhi[2]) | ((unsigned)f2bf(vhi[3]) << 16);
      const uint4v uu = {u0, u1, u2, u3};
      const short8 af = __builtin_bit_cast(short8, uu);

      acc0 = __builtin_amdgcn_mfma_f32_16x16x32_bf16(af, bp[kk * 64 + lane], acc0, 0, 0, 0);
      acc1 = __builtin_amdgcn_mfma_f32_16x16x32_bf16(af, bp[(9 + kk) * 64 + lane], acc1, 0, 0, 0);
    }

    // D layout: col = lane&15, row = qq*4 + reg
    float* op = out + (size_t)(P0 + qq * 4) * 32 + (lane & 15);
#pragma unroll
    for (int r = 0; r < 4; ++r) {
      op[r * 32] = acc0[r];
      op[r * 32 + 16] = acc1[r];
    }
  }
}

extern "C" void kernel_launch(void* const* d_in, const int* in_sizes, int n_in,
                              void* d_out, int out_size, void* d_ws, size_t ws_size,
                              hipStream_t stream) {
  const float* x    = (const float*)d_in[0];
  const float* off  = (const float*)d_in[1];
  const float* kern = (const float*)d_in[2];
  const float* bias = (const float*)d_in[3];
  float* out = (float*)d_out;
  // 294912 pixels / (4 waves * 16 px * NB batches) = 2304 blocks
  deform_conv_kernel<<<dim3(2304), dim3(256), 0, stream>>>(x, off, kern, bias, out);
}

// Round 3
// 229.063 us; speedup vs baseline: 1.1202x; 1.1202x over previous
//
#include <hip/hip_runtime.h>

typedef short short8 __attribute__((ext_vector_type(8)));
typedef float f32x4 __attribute__((ext_vector_type(4)));
typedef unsigned int uint4v __attribute__((ext_vector_type(4)));

#define H_ 384
#define W_ 384
#define C_ 32
#define F_ 32
#define HW_ 147456          // H_*W_
#define HP1F 385.0f         // (H+2*pad)-1 as float
#define NB 2                // pixel batches per wave

__device__ __forceinline__ unsigned short f2bf(float f) {
  unsigned int u = __float_as_uint(f);
  u += 0x7fffu + ((u >> 16) & 1u);   // RNE
  return (unsigned short)(u >> 16);
}

__global__ __launch_bounds__(256) void deform_conv_kernel(
    const float* __restrict__ x, const float* __restrict__ off,
    const float* __restrict__ kern, const float* __restrict__ bias,
    float* __restrict__ out) {
  // LDS: 9216 shorts (18.4 KB) holding the packed bf16 B fragments (MFMA
  // B-operand layout) for all 9 taps x 2 f-tiles. Written once, one barrier,
  // then read-only (2 conflict-free ds_read_b128 per tap). No A-side LDS:
  // each lane computes its own A fragment directly (pixel = lane&15 = A row,
  // channels qq*8..+7 = its K slice).
  // R3 fix vs R2: NO offset register array (ofs[9] was runtime-indexed ->
  // scratch -> 180 MB of spill traffic, the whole R2 regression). Offsets
  // are loaded per tap through two NAMED float2 regs (one-tap prefetch),
  // spill-proof whether or not the tap loop unrolls.
  __shared__ short ldsB[9216];

  const int tid = threadIdx.x;
  const int lane = tid & 63;

  // ---- stage packed B fragments (bf16, MFMA B-operand layout) into LDS ----
  {
    unsigned short* pk = (unsigned short*)ldsB;
    for (int e = tid; e < 1152; e += 256) {   // 2 f-tiles * 9 k-steps * 64 lanes
      const int ln = e & 63;
      const int kk = (e >> 6) % 9;
      const int nt = e / 576;
      const int f = nt * 16 + (ln & 15);
      const int q2 = ln >> 4;
      unsigned short rr[8];
#pragma unroll
      for (int i2 = 0; i2 < 8; ++i2) {
        const int c = q2 * 8 + i2;                     // contraction idx = kk*32 + c
        rr[i2] = f2bf(kern[(kk * 32 + c) * 32 + f]);
      }
      uint4 w;
      w.x = rr[0] | ((unsigned)rr[1] << 16);
      w.y = rr[2] | ((unsigned)rr[3] << 16);
      w.z = rr[4] | ((unsigned)rr[5] << 16);
      w.w = rr[6] | ((unsigned)rr[7] << 16);
      *(uint4*)&pk[e * 8] = w;
    }
    __syncthreads();   // only barrier in the kernel; LDS is read-only after
  }
  const short8* bp = (const short8*)ldsB;

  const float bias0 = bias[lane & 15];
  const float bias1 = bias[16 + (lane & 15)];

  const int mrow = lane & 15;       // pixel within 16-group == MFMA A row
  const int qq = lane >> 4;         // MFMA K-quad: this lane feeds c = qq*8..+7
  const int c0 = qq * 8;

  // XCD-aware swizzle: physical block p lands on XCD p%8; give each XCD a
  // contiguous run of 288 logical blocks (96 contiguous image rows) so its
  // 4 MiB L2 holds the streaming reuse window and the halo is fetched by
  // exactly one XCD. Bijection over [0,2304): blk=8q+r -> 288r+q.
  const int lb = (blockIdx.x & 7) * 288 + (blockIdx.x >> 3);

  for (int nb = 0; nb < NB; ++nb) {
    const int g = lb * (4 * NB) + nb * 4 + (tid >> 6);   // wave-group index
    const int P0 = g << 4;                               // first of 16 pixels
    const int b = (P0 >= HW_) ? 1 : 0;
    const int rem = P0 - b * HW_;
    const int i = rem / W_;
    const int j0 = rem - i * W_;     // group never crosses a row (W%16==0)
    const int j = j0 + mrow;         // this lane's pixel column

    const float* opix = off + (size_t)(i * W_ + j) * 18;

    f32x4 acc0 = {bias0, bias0, bias0, bias0};
    f32x4 acc1 = {bias1, bias1, bias1, bias1};

    // One-tap offset prefetch through named registers (no array -> no scratch)
    float2 ocur = *(const float2*)(opix);

    // ---- per-tap: gather 4 corners x 8 channels, interp, MFMA directly ----
#pragma unroll
    for (int kk = 0; kk < 9; ++kk) {
      float2 onext = ocur;
      if (kk < 8) onext = *(const float2*)(opix + (kk + 1) * 2);

      const int di = kk / 3;
      const int dj = kk - di * 3;
      float yf = (float)(i + di) + ocur.y;   // padded coords; .y = y_off
      float xf = (float)(j + dj) + ocur.x;   // .x = x_off
      yf = fminf(fmaxf(yf, 0.f), HP1F);
      xf = fminf(fmaxf(xf, 0.f), HP1F);
      const float y0f = floorf(yf);
      const float x0f = floorf(xf);
      const int y0 = (int)y0f;
      const int x0 = (int)x0f;

      f32x4 vlo, vhi;
      // Fast path: all 4 corners strictly inside the image; wave-uniform
      // branch via __all (covers 16 pixels; offsets ~N(0,1)).
      const int fast = ((unsigned)(y0 - 1) < 383u) & ((unsigned)(x0 - 1) < 383u);
      if (__all(fast)) {
        const float wy1 = yf - y0f;
        const float wy0 = (y0f + 1.0f) - yf;   // == (float)y1 - yf, y1=y0+1
        const float wx1 = xf - x0f;
        const float wx0 = (x0f + 1.0f) - xf;
        const float w00 = wy0 * wx0, w01 = wy0 * wx1;
        const float w10 = wy1 * wx0, w11 = wy1 * wx1;
        const int base00 = ((b * H_ + (y0 - 1)) * W_ + (x0 - 1)) * C_ + c0;
        // 8 unconditional, independent 16B gathers -> all in flight together
        const f32x4 p00l = *(const f32x4*)(x + base00);
        const f32x4 p00h = *(const f32x4*)(x + base00 + 4);
        const f32x4 p01l = *(const f32x4*)(x + base00 + C_);
        const f32x4 p01h = *(const f32x4*)(x + base00 + C_ + 4);
        const f32x4 p10l = *(const f32x4*)(x + base00 + W_ * C_);
        const f32x4 p10h = *(const f32x4*)(x + base00 + W_ * C_ + 4);
        const f32x4 p11l = *(const f32x4*)(x + base00 + W_ * C_ + C_);
        const f32x4 p11h = *(const f32x4*)(x + base00 + W_ * C_ + C_ + 4);
        vlo = w00 * p00l + w01 * p01l + w10 * p10l + w11 * p11l;
        vhi = w00 * p00h + w01 * p01h + w10 * p10h + w11 * p11h;
      } else {
        // Slow path: verbatim R0 logic (guarded loads, pad corners -> 0).
        const int y1 = min(y0 + 1, 385);
        const int x1 = min(x0 + 1, 385);
        const float wy1 = yf - y0f;
        const float wy0 = (float)y1 - yf;
        const float wx1 = xf - x0f;
        const float wx0 = (float)x1 - xf;
        const float w00 = wy0 * wx0, w01 = wy0 * wx1;
        const float w10 = wy1 * wx0, w11 = wy1 * wx1;

        const int yu0 = y0 - 1, xu0 = x0 - 1;
        const bool vy0 = (unsigned)yu0 < 384u, vy1 = (unsigned)(y1 - 1) < 384u;
        const bool vx0 = (unsigned)xu0 < 384u, vx1 = (unsigned)(x1 - 1) < 384u;
        const int base00 = ((b * H_ + yu0) * W_ + xu0) * C_ + c0;
        const int ddx = (x1 - x0) * C_;
        const int ddy = (y1 - y0) * (W_ * C_);
        const f32x4 z = {0.f, 0.f, 0.f, 0.f};
        f32x4 p00l = z, p00h = z, p01l = z, p01h = z;
        f32x4 p10l = z, p10h = z, p11l = z, p11h = z;
        if (vy0 && vx0) { p00l = *(const f32x4*)(x + base00);
                          p00h = *(const f32x4*)(x + base00 + 4); }
        if (vy0 && vx1) { p01l = *(const f32x4*)(x + base00 + ddx);
                          p01h = *(const f32x4*)(x + base00 + ddx + 4); }
        if (vy1 && vx0) { p10l = *(const f32x4*)(x + base00 + ddy);
                          p10h = *(const f32x4*)(x + base00 + ddy + 4); }
        if (vy1 && vx1) { p11l = *(const f32x4*)(x + base00 + ddy + ddx);
                          p11h = *(const f32x4*)(x + base00 + ddy + ddx + 4); }
        vlo = w00 * p00l + w01 * p01l + w10 * p10l + w11 * p11l;
        vhi = w00 * p00h + w01 * p01h + w10 * p10h + w11 * p11h;
      }

      // pack this lane's A fragment: 8 bf16 = channels c0..c0+7 of its pixel
      const unsigned u0 = f2bf(vlo[0]) | ((unsigned)f2bf(vlo[1]) << 16);
      const unsigned u1 = f2bf(vlo[2]) | ((unsigned)f2bf(vlo[3]) << 16);
      const unsigned u2 = f2bf(vhi[0]) | ((unsigned)f2bf(vhi[1]) << 16);
      const unsigned u3 = f2bf(vhi[2]) | ((unsigned)f2bf(vhi[3]) << 16);
      const uint4v uu = {u0, u1, u2, u3};
      const short8 af = __builtin_bit_cast(short8, uu);

      acc0 = __builtin_amdgcn_mfma_f32_16x16x32_bf16(af, bp[kk * 64 + lane], acc0, 0, 0, 0);
      acc1 = __builtin_amdgcn_mfma_f32_16x16x32_bf16(af, bp[(9 + kk) * 64 + lane], acc1, 0, 0, 0);

      ocur = onext;
    }

    // D layout: col = lane&15, row = qq*4 + reg
    float* op = out + (size_t)(P0 + qq * 4) * 32 + (lane & 15);
#pragma unroll
    for (int r = 0; r < 4; ++r) {
      op[r * 32] = acc0[r];
      op[r * 32 + 16] = acc1[r];
    }
  }
}

extern "C" void kernel_launch(void* const* d_in, const int* in_sizes, int n_in,
                              void* d_out, int out_size, void* d_ws, size_t ws_size,
                              hipStream_t stream) {
  const float* x    = (const float*)d_in[0];
  const float* off  = (const float*)d_in[1];
  const float* kern = (const float*)d_in[2];
  const float* bias = (const float*)d_in[3];
  float* out = (float*)d_out;
  // 294912 pixels / (4 waves * 16 px * NB batches) = 2304 blocks
  deform_conv_kernel<<<dim3(2304), dim3(256), 0, stream>>>(x, off, kern, bias, out);
}

// Round 4
// 165.877 us; speedup vs baseline: 1.5468x; 1.3809x over previous
//
#include <hip/hip_runtime.h>

typedef short short8 __attribute__((ext_vector_type(8)));
typedef float f32x4 __attribute__((ext_vector_type(4)));
typedef unsigned int uint4v __attribute__((ext_vector_type(4)));

#define H_ 384
#define W_ 384
#define C_ 32
#define HW_ 147456          // H_*W_
#define HP1F 385.0f         // (H+2*pad)-1 as float
#define NB 2                // pixel batches per wave

__device__ __forceinline__ unsigned short f2bf(float f) {
  unsigned int u = __float_as_uint(f);
  u += 0x7fffu + ((u >> 16) & 1u);   // RNE
  return (unsigned short)(u >> 16);
}

__device__ __forceinline__ unsigned pack2(float a, float b) {
  return (unsigned)f2bf(a) | ((unsigned)f2bf(b) << 16);
}

// General (guarded) bilinear sample: verbatim R0 slow-path arithmetic.
// Identical results to the fast path for interior points.
__device__ __forceinline__ f32x4 sample_general(
    const float* __restrict__ x, float2 o, int i, int di, int j, int dj,
    int b, int c0) {
  float yf = (float)(i + di) + o.y;
  float xf = (float)(j + dj) + o.x;
  yf = fminf(fmaxf(yf, 0.f), HP1F);
  xf = fminf(fmaxf(xf, 0.f), HP1F);
  const float y0f = floorf(yf);
  const float x0f = floorf(xf);
  const int y0 = (int)y0f;
  const int x0 = (int)x0f;
  const int y1 = min(y0 + 1, 385);
  const int x1 = min(x0 + 1, 385);
  const float wy1 = yf - y0f;
  const float wy0 = (float)y1 - yf;
  const float wx1 = xf - x0f;
  const float wx0 = (float)x1 - xf;
  const float w00 = wy0 * wx0, w01 = wy0 * wx1;
  const float w10 = wy1 * wx0, w11 = wy1 * wx1;

  const int yu0 = y0 - 1, xu0 = x0 - 1;
  const bool vy0 = (unsigned)yu0 < 384u, vy1 = (unsigned)(y1 - 1) < 384u;
  const bool vx0 = (unsigned)xu0 < 384u, vx1 = (unsigned)(x1 - 1) < 384u;
  const int base00 = ((b * H_ + yu0) * W_ + xu0) * C_ + c0;
  const int ddx = (x1 - x0) * C_;
  const int ddy = (y1 - y0) * (W_ * C_);
  const f32x4 z = {0.f, 0.f, 0.f, 0.f};
  f32x4 p00 = z, p01 = z, p10 = z, p11 = z;
  if (vy0 && vx0) p00 = *(const f32x4*)(x + base00);
  if (vy0 && vx1) p01 = *(const f32x4*)(x + base00 + ddx);
  if (vy1 && vx0) p10 = *(const f32x4*)(x + base00 + ddy);
  if (vy1 && vx1) p11 = *(const f32x4*)(x + base00 + ddy + ddx);
  return w00 * p00 + w01 * p01 + w10 * p10 + w11 * p11;
}

__global__ __launch_bounds__(256) void deform_conv_kernel(
    const float* __restrict__ x, const float* __restrict__ off,
    const float* __restrict__ kern, const float* __restrict__ bias,
    float* __restrict__ out) {
  // LDS: 9216 shorts (18.4 KB) = packed bf16 B fragments, written once,
  // one barrier, read-only after (2 conflict-free ds_read_b128 per tap).
  //
  // R4 structure: gathers use the R0 COALESCED mapping (lane = slot*8 +
  // channel-quad, so 8 consecutive lanes read one pixel-corner's 128 B
  // contiguously -> 16 unique lines per VMEM instr, each line touched
  // once). Interp results are redistributed to the MFMA A-fragment lane
  // layout with 8 ds_bpermute + 4 selects per tap -- replacing both R0's
  // LDS slab roundtrip (write->drain->read serialization, 2M conflict
  // cycles) and R3's uncoalesced direct-MFMA gathers (2x line touches).
  __shared__ short ldsB[9216];

  const int tid = threadIdx.x;
  const int lane = tid & 63;

  // ---- stage packed B fragments (bf16, MFMA B-operand layout) into LDS ----
  {
    unsigned short* pk = (unsigned short*)ldsB;
    for (int e = tid; e < 1152; e += 256) {   // 2 f-tiles * 9 k-steps * 64 lanes
      const int ln = e & 63;
      const int kk = (e >> 6) % 9;
      const int nt = e / 576;
      const int f = nt * 16 + (ln & 15);
      const int q2 = ln >> 4;
      unsigned short rr[8];
#pragma unroll
      for (int i2 = 0; i2 < 8; ++i2) {
        const int c = q2 * 8 + i2;                     // contraction idx = kk*32 + c
        rr[i2] = f2bf(kern[(kk * 32 + c) * 32 + f]);
      }
      uint4 w;
      w.x = rr[0] | ((unsigned)rr[1] << 16);
      w.y = rr[2] | ((unsigned)rr[3] << 16);
      w.z = rr[4] | ((unsigned)rr[5] << 16);
      w.w = rr[6] | ((unsigned)rr[7] << 16);
      *(uint4*)&pk[e * 8] = w;
    }
    __syncthreads();   // only barrier in the kernel; LDS is read-only after
  }
  const short8* bp = (const short8*)ldsB;

  const float bias0 = bias[lane & 15];
  const float bias1 = bias[16 + (lane & 15)];

  // gather-lane mapping (R0 style): 8 lanes cover one pixel-corner row
  const int q  = lane >> 3;         // pixel slot within 8
  const int cq = lane & 7;          // channel quad
  const int c0 = cq * 4;

  // MFMA-lane mapping (destination of the redistribution)
  const int mrow = lane & 15;       // A row = pixel within 16-group
  const int qq = lane >> 4;         // A K-slice: channels qq*8..+7
  // bpermute byte-addresses of the two source lanes feeding this dest lane
  const int sl0 = (((mrow & 7) << 3) + (qq << 1)) << 2;
  const int sl1 = sl0 + 4;
  const bool hi = (mrow & 8) != 0;  // phase select: pixels 8..15 come from phase B

  // XCD-aware swizzle: bijection over [0,2304): blk=8r+q -> 288r+q, so each
  // XCD gets 96 contiguous image rows and fetches its halo exactly once.
  const int lb = (blockIdx.x & 7) * 288 + (blockIdx.x >> 3);

  for (int nb = 0; nb < NB; ++nb) {
    const int g = lb * (4 * NB) + nb * 4 + (tid >> 6);   // wave-group index
    const int P0 = g << 4;                               // first of 16 pixels
    const int b = (P0 >= HW_) ? 1 : 0;
    const int rem = P0 - b * HW_;
    const int i = rem / W_;
    const int j0 = rem - i * W_;     // group never crosses a row (W%16==0)
    const int jA = j0 + q;           // phase-A pixel (m = q)
    const int jB = j0 + 8 + q;       // phase-B pixel (m = 8+q)

    const float* opixA = off + (size_t)(i * W_ + jA) * 18;
    const float* opixB = off + (size_t)(i * W_ + jB) * 18;

    f32x4 acc0 = {bias0, bias0, bias0, bias0};
    f32x4 acc1 = {bias1, bias1, bias1, bias1};

    // one-tap offset prefetch through NAMED registers (no array -> no scratch)
    float2 oA = *(const float2*)(opixA);
    float2 oB = *(const float2*)(opixB);

#pragma unroll
    for (int kk = 0; kk < 9; ++kk) {
      float2 oAn = oA, oBn = oB;
      if (kk < 8) {
        oAn = *(const float2*)(opixA + (kk + 1) * 2);
        oBn = *(const float2*)(opixB + (kk + 1) * 2);
      }
      const int di = kk / 3;
      const int dj = kk - di * 3;

      // coords for both phases, then ONE wave-uniform fast/slow branch so all
      // 8 corner gathers issue together (max MLP)
      float yfA = (float)(i + di) + oA.y;
      float xfA = (float)(jA + dj) + oA.x;
      yfA = fminf(fmaxf(yfA, 0.f), HP1F);
      xfA = fminf(fmaxf(xfA, 0.f), HP1F);
      const float y0fA = floorf(yfA), x0fA = floorf(xfA);
      const int y0A = (int)y0fA, x0A = (int)x0fA;

      float yfB = (float)(i + di) + oB.y;
      float xfB = (float)(jB + dj) + oB.x;
      yfB = fminf(fmaxf(yfB, 0.f), HP1F);
      xfB = fminf(fmaxf(xfB, 0.f), HP1F);
      const float y0fB = floorf(yfB), x0fB = floorf(xfB);
      const int y0B = (int)y0fB, x0B = (int)x0fB;

      const int fastA = ((unsigned)(y0A - 1) < 383u) & ((unsigned)(x0A - 1) < 383u);
      const int fastB = ((unsigned)(y0B - 1) < 383u) & ((unsigned)(x0B - 1) < 383u);

      f32x4 vA, vB;
      if (__all(fastA & fastB)) {
        const int baseA = ((b * H_ + (y0A - 1)) * W_ + (x0A - 1)) * C_ + c0;
        const int baseB = ((b * H_ + (y0B - 1)) * W_ + (x0B - 1)) * C_ + c0;
        // 8 unconditional independent 16B gathers, 8-lane-contiguous each
        const f32x4 pA00 = *(const f32x4*)(x + baseA);
        const f32x4 pA01 = *(const f32x4*)(x + baseA + C_);
        const f32x4 pA10 = *(const f32x4*)(x + baseA + W_ * C_);
        const f32x4 pA11 = *(const f32x4*)(x + baseA + W_ * C_ + C_);
        const f32x4 pB00 = *(const f32x4*)(x + baseB);
        const f32x4 pB01 = *(const f32x4*)(x + baseB + C_);
        const f32x4 pB10 = *(const f32x4*)(x + baseB + W_ * C_);
        const f32x4 pB11 = *(const f32x4*)(x + baseB + W_ * C_ + C_);

        const float wy1A = yfA - y0fA, wy0A = (y0fA + 1.0f) - yfA;
        const float wx1A = xfA - x0fA, wx0A = (x0fA + 1.0f) - xfA;
        vA = (wy0A * wx0A) * pA00 + (wy0A * wx1A) * pA01 +
             (wy1A * wx0A) * pA10 + (wy1A * wx1A) * pA11;

        const float wy1B = yfB - y0fB, wy0B = (y0fB + 1.0f) - yfB;
        const float wx1B = xfB - x0fB, wx0B = (x0fB + 1.0f) - xfB;
        vB = (wy0B * wx0B) * pB00 + (wy0B * wx1B) * pB01 +
             (wy1B * wx0B) * pB10 + (wy1B * wx1B) * pB11;
      } else {
        vA = sample_general(x, oA, i, di, jA, dj, b, c0);
        vB = sample_general(x, oB, i, di, jB, dj, b, c0);
      }

      // pack 4 channels -> 2 bf16x2 words per phase
      const int a0 = (int)pack2(vA[0], vA[1]);
      const int a1 = (int)pack2(vA[2], vA[3]);
      const int b0 = (int)pack2(vB[0], vB[1]);
      const int b1 = (int)pack2(vB[2], vB[3]);

      // redistribute to MFMA A-fragment layout: 8 bpermute + 4 selects.
      // dest lane (mrow,qq): W0,W1 from source lane sl0 (ch 8qq..+3),
      // W2,W3 from sl1 (ch 8qq+4..+7); phase by mrow>>3.
      const int pa0 = __builtin_amdgcn_ds_bpermute(sl0, a0);
      const int pb0 = __builtin_amdgcn_ds_bpermute(sl0, b0);
      const int pa1 = __builtin_amdgcn_ds_bpermute(sl0, a1);
      const int pb1 = __builtin_amdgcn_ds_bpermute(sl0, b1);
      const int pa2 = __builtin_amdgcn_ds_bpermute(sl1, a0);
      const int pb2 = __builtin_amdgcn_ds_bpermute(sl1, b0);
      const int pa3 = __builtin_amdgcn_ds_bpermute(sl1, a1);
      const int pb3 = __builtin_amdgcn_ds_bpermute(sl1, b1);
      const uint4v uu = {(unsigned)(hi ? pb0 : pa0), (unsigned)(hi ? pb1 : pa1),
                         (unsigned)(hi ? pb2 : pa2), (unsigned)(hi ? pb3 : pa3)};
      const short8 af = __builtin_bit_cast(short8, uu);

      acc0 = __builtin_amdgcn_mfma_f32_16x16x32_bf16(af, bp[kk * 64 + lane], acc0, 0, 0, 0);
      acc1 = __builtin_amdgcn_mfma_f32_16x16x32_bf16(af, bp[(9 + kk) * 64 + lane], acc1, 0, 0, 0);

      oA = oAn;
      oB = oBn;
    }

    // D layout: col = lane&15, row = qq*4 + reg
    float* op = out + (size_t)(P0 + qq * 4) * 32 + (lane & 15);
#pragma unroll
    for (int r = 0; r < 4; ++r) {
      op[r * 32] = acc0[r];
      op[r * 32 + 16] = acc1[r];
    }
  }
}

extern "C" void kernel_launch(void* const* d_in, const int* in_sizes, int n_in,
                              void* d_out, int out_size, void* d_ws, size_t ws_size,
                              hipStream_t stream) {
  const float* x    = (const float*)d_in[0];
  const float* off  = (const float*)d_in[1];
  const float* kern = (const float*)d_in[2];
  const float* bias = (const float*)d_in[3];
  float* out = (float*)d_out;
  // 294912 pixels / (4 waves * 16 px * NB batches) = 2304 blocks
  deform_conv_kernel<<<dim3(2304), dim3(256), 0, stream>>>(x, off, kern, bias, out);
}